// Round 5
// baseline (68.821 us; speedup 1.0000x reference)
//
#include <hip/hip_runtime.h>
#include <math.h>

#define BB 64
#define TT 2048
#define EH 512   // ENC_H
#define DH 512   // DEC_H
#define PP 256   // P
#define NC 16            // chunks per batch row
#define TC (TT / NC)     // 128 t-rows per chunk
#define ROWS_PER_WAVE (TC / 4)   // 32

typedef float vfloat4 __attribute__((ext_vector_type(4)));

// ---------------------------------------------------------------------------
// K1: q[b,p] = dec[b,:] . Wq[:,p] + bq[p]
// grid = B*4 (p-quarters), 256 thr.
// ---------------------------------------------------------------------------
__global__ __launch_bounds__(256) void k_qproj(
    const float* __restrict__ dec, const float* __restrict__ Wq,
    const float* __restrict__ bq, float* __restrict__ q)
{
    const int b  = blockIdx.x >> 2;
    const int pq = blockIdx.x & 3;
    const int tid = threadIdx.x;
    const int p  = pq * 64 + (tid & 63);
    const int dc = tid >> 6;

    float acc = 0.f;
    const float* decb = dec + b * DH;
    #pragma unroll 8
    for (int d = dc * 128; d < dc * 128 + 128; ++d)
        acc = fmaf(decb[d], Wq[d * PP + p], acc);

    __shared__ float s_red[256];
    s_red[tid] = acc;
    __syncthreads();
    if (tid < 64) {
        float r = s_red[tid] + s_red[tid + 64] + s_red[tid + 128] + s_red[tid + 192];
        q[b * PP + p] = r + bq[p];
    }
}

// ---------------------------------------------------------------------------
// K2: qk[b,e] = Wk[e,:] . q[b,:]
// grid = B*32 (16 e's per block), 256 thr = 16 groups of 16 lanes.
// ---------------------------------------------------------------------------
__global__ __launch_bounds__(256) void k_kfold(
    const float* __restrict__ Wk, const float* __restrict__ q,
    float* __restrict__ qk)
{
    const int b   = blockIdx.x >> 5;
    const int et  = blockIdx.x & 31;
    const int grp = threadIdx.x >> 4;
    const int l16 = threadIdx.x & 15;
    const int e   = et * 16 + grp;

    const float* wrow = Wk + e * PP;
    const float* qb   = q + b * PP;

    float acc = 0.f;
    #pragma unroll
    for (int k = 0; k < 4; ++k) {
        const float4 w  = *(const float4*)(wrow + l16 * 4 + k * 64);
        const float4 qv = *(const float4*)(qb   + l16 * 4 + k * 64);
        acc += w.x * qv.x + w.y * qv.y + w.z * qv.z + w.w * qv.w;
    }
    #pragma unroll
    for (int off = 1; off < 16; off <<= 1)
        acc += __shfl_xor(acc, off, 64);
    if (l16 == 0) qk[b * EH + e] = acc;
}

// ---------------------------------------------------------------------------
// K3: streaming pass over enc with online softmax.
// grid = B*NC = 1024 blocks, 256 thr (4 waves), 32 rows/wave.
// Prefetch depth 4 rows (6 live row-buffers), full unroll -> static indices.
// Raw scores staged in LDS, one coalesced block store at the end.
// ---------------------------------------------------------------------------
__global__ __launch_bounds__(256) void attn_main(
    const float* __restrict__ enc,   // [B, T, EH]
    const float* __restrict__ qk,    // [B, EH]
    float* __restrict__ raw,         // [B, T]  (attn region of d_out)
    float* __restrict__ mc,          // [B, NC]
    float* __restrict__ lc,          // [B, NC]
    float* __restrict__ ctxc)        // [B, NC, EH]
{
    const int blk  = blockIdx.x;
    const int b    = blk / NC;
    const int c    = blk % NC;
    const int tid  = threadIdx.x;
    const int wave = tid >> 6;
    const int lane = tid & 63;
    const int e0   = lane * 4;

    const float* encb = enc + (size_t)b * TT * EH;

    const float4 qk0 = *(const float4*)(qk + b * EH + e0);
    const float4 qk1 = *(const float4*)(qk + b * EH + 256 + e0);

    float  m = -1e30f, l = 0.f;
    float4 ctx0 = {0.f, 0.f, 0.f, 0.f};
    float4 ctx1 = {0.f, 0.f, 0.f, 0.f};

    __shared__ float s_raw[TC];
    const int tbase = c * TC + wave;          // rows: tbase + 4*it

    // 6-slot row pipeline, all indices compile-time via full unroll
    vfloat4 buf[6][2];
    #pragma unroll
    for (int r = 0; r < 4; ++r) {
        const vfloat4* rp = (const vfloat4*)(encb + (size_t)(tbase + 4 * r) * EH);
        buf[r][0] = __builtin_nontemporal_load(rp + lane);
        buf[r][1] = __builtin_nontemporal_load(rp + 64 + lane);
    }

    #pragma unroll
    for (int it = 0; it < ROWS_PER_WAVE; ++it) {
        const int pf = it + 4;
        if (pf < ROWS_PER_WAVE) {
            const vfloat4* rp = (const vfloat4*)(encb + (size_t)(tbase + 4 * pf) * EH);
            buf[pf % 6][0] = __builtin_nontemporal_load(rp + lane);
            buf[pf % 6][1] = __builtin_nontemporal_load(rp + 64 + lane);
        }
        const vfloat4 a0 = buf[it % 6][0];
        const vfloat4 a1 = buf[it % 6][1];

        float d = a0.x * qk0.x + a0.y * qk0.y + a0.z * qk0.z + a0.w * qk0.w
                + a1.x * qk1.x + a1.y * qk1.y + a1.z * qk1.z + a1.w * qk1.w;
        #pragma unroll
        for (int off = 32; off > 0; off >>= 1)
            d += __shfl_xor(d, off, 64);
        const float s = d;

        if (lane == 0) s_raw[wave + 4 * it] = s;

        const float mn    = fmaxf(m, s);
        const float scale = __expf(m - mn);
        const float p     = __expf(s - mn);
        l = l * scale + p;
        ctx0.x = ctx0.x * scale + p * a0.x;
        ctx0.y = ctx0.y * scale + p * a0.y;
        ctx0.z = ctx0.z * scale + p * a0.z;
        ctx0.w = ctx0.w * scale + p * a0.w;
        ctx1.x = ctx1.x * scale + p * a1.x;
        ctx1.y = ctx1.y * scale + p * a1.y;
        ctx1.z = ctx1.z * scale + p * a1.z;
        ctx1.w = ctx1.w * scale + p * a1.w;
        m = mn;
    }

    // merge the 4 waves of this block
    __shared__ float s_m[4], s_l[4];
    __shared__ float s_ctx[4][EH];
    *(float4*)&s_ctx[wave][e0]       = ctx0;
    *(float4*)&s_ctx[wave][256 + e0] = ctx1;
    if (lane == 0) { s_m[wave] = m; s_l[wave] = l; }
    __syncthreads();

    // coalesced raw-score store for this chunk (128 consecutive floats)
    if (tid < TC) raw[(size_t)b * TT + c * TC + tid] = s_raw[tid];

    const float mb = fmaxf(fmaxf(s_m[0], s_m[1]), fmaxf(s_m[2], s_m[3]));
    const float w0 = __expf(s_m[0] - mb);
    const float w1 = __expf(s_m[1] - mb);
    const float w2 = __expf(s_m[2] - mb);
    const float w3 = __expf(s_m[3] - mb);

    if (tid == 0) {
        mc[b * NC + c] = mb;
        lc[b * NC + c] = s_l[0] * w0 + s_l[1] * w1 + s_l[2] * w2 + s_l[3] * w3;
    }
    float* cdst = ctxc + ((size_t)b * NC + c) * EH;
    for (int e = tid; e < EH; e += 256)
        cdst[e] = s_ctx[0][e] * w0 + s_ctx[1][e] * w1
                + s_ctx[2][e] * w2 + s_ctx[3][e] * w3;
}

// ---------------------------------------------------------------------------
// K4: per (b, p-quarter): merge chunk partials, context = sctx@Wv + bv,
// rewrite attn quarter. grid = B*4 = 256 blocks.
// ---------------------------------------------------------------------------
__global__ __launch_bounds__(256) void k_finish(
    const float* __restrict__ mc,    // [B, NC]
    const float* __restrict__ lc,    // [B, NC]
    const float* __restrict__ ctxc,  // [B, NC, EH]
    const float* __restrict__ Wv,    // [EH, PP]
    const float* __restrict__ bv,    // [PP]
    float* __restrict__ out_ctx,     // [B, PP]
    float* __restrict__ attn)        // [B, T] (holds raw on entry)
{
    const int b   = blockIdx.x >> 2;
    const int pq  = blockIdx.x & 3;
    const int tid = threadIdx.x;

    float m = -1e30f;
    #pragma unroll
    for (int i = 0; i < NC; ++i) m = fmaxf(m, mc[b * NC + i]);
    float l = 0.f;
    #pragma unroll
    for (int i = 0; i < NC; ++i) l += lc[b * NC + i] * __expf(mc[b * NC + i] - m);
    const float inv_l = 1.0f / l;

    __shared__ float s_w[NC];
    __shared__ float s_ctx[EH];
    if (tid < NC) s_w[tid] = __expf(mc[b * NC + tid] - m);
    __syncthreads();

    for (int e = tid; e < EH; e += 256) {
        float acc = 0.f;
        #pragma unroll
        for (int i = 0; i < NC; ++i)
            acc += ctxc[((size_t)b * NC + i) * EH + e] * s_w[i];
        s_ctx[e] = acc * inv_l;
    }
    __syncthreads();

    const int p  = pq * 64 + (tid & 63);
    const int dc = tid >> 6;
    float acc = 0.f;
    #pragma unroll 8
    for (int e = dc * 128; e < dc * 128 + 128; ++e)
        acc = fmaf(s_ctx[e], Wv[e * PP + p], acc);

    __shared__ float s_red[256];
    s_red[tid] = acc;
    __syncthreads();
    if (tid < 64)
        out_ctx[b * PP + p] = s_red[tid] + s_red[tid + 64]
                            + s_red[tid + 128] + s_red[tid + 192] + bv[p];

    #pragma unroll
    for (int i = 0; i < TT / 4 / 256; ++i) {
        const int t = pq * (TT / 4) + i * 256 + tid;
        const float r = attn[(size_t)b * TT + t];
        attn[(size_t)b * TT + t] = __expf(r - m) * inv_l;
    }
}

// ---------------------------------------------------------------------------
extern "C" void kernel_launch(void* const* d_in, const int* in_sizes, int n_in,
                              void* d_out, int out_size, void* d_ws, size_t ws_size,
                              hipStream_t stream) {
    const float* dec = (const float*)d_in[0];
    const float* enc = (const float*)d_in[1];
    // d_in[2] = encoder_lens: unused by the reference computation
    const float* Wk  = (const float*)d_in[3];
    // d_in[4] = bk: drops out (softmax shift invariance)
    const float* Wv  = (const float*)d_in[5];
    const float* bv  = (const float*)d_in[6];
    const float* Wq  = (const float*)d_in[7];
    const float* bq  = (const float*)d_in[8];

    float* out_ctx = (float*)d_out;              // [B, PP]
    float* attn    = out_ctx + BB * PP;          // [B, T]

    float* q    = (float*)d_ws;                  // B*PP
    float* qk   = q + BB * PP;                   // B*EH
    float* mc   = qk + BB * EH;                  // B*NC
    float* lc   = mc + BB * NC;                  // B*NC
    float* ctxc = lc + BB * NC;                  // B*NC*EH

    k_qproj<<<BB * 4, 256, 0, stream>>>(dec, Wq, bq, q);
    k_kfold<<<BB * 32, 256, 0, stream>>>(Wk, q, qk);
    attn_main<<<BB * NC, 256, 0, stream>>>(enc, qk, attn, mc, lc, ctxc);
    k_finish<<<BB * 4, 256, 0, stream>>>(mc, lc, ctxc, Wv, bv, out_ctx, attn);
}

// Round 6
// 61.311 us; speedup vs baseline: 1.1225x; 1.1225x over previous
//
#include <hip/hip_runtime.h>
#include <math.h>

#define BB 64
#define TT 2048
#define EH 512   // ENC_H
#define DH 512   // DEC_H
#define PP 256   // P
#define NC 8             // chunks per batch row
#define TC (TT / NC)     // 256 t-rows per chunk
#define WPB 8            // waves per block in attn_main
#define ROWS_PER_WAVE (TC / WPB)   // 32

typedef float vfloat4 __attribute__((ext_vector_type(4)));

// ---------------------------------------------------------------------------
// K1: q[b,p] = dec[b,:] . Wq[:,p] + bq[p]
// grid = B*4 (p-quarters), 256 thr. 4 accumulators break the fp32 FMA chain.
// ---------------------------------------------------------------------------
__global__ __launch_bounds__(256) void k_qproj(
    const float* __restrict__ dec, const float* __restrict__ Wq,
    const float* __restrict__ bq, float* __restrict__ q)
{
    const int b  = blockIdx.x >> 2;
    const int pq = blockIdx.x & 3;
    const int tid = threadIdx.x;
    const int p  = pq * 64 + (tid & 63);
    const int dc = tid >> 6;

    const float* decb = dec + b * DH;
    float a0 = 0.f, a1 = 0.f, a2 = 0.f, a3 = 0.f;
    #pragma unroll 8
    for (int d = dc * 128; d < dc * 128 + 128; d += 4) {
        a0 = fmaf(decb[d + 0], Wq[(d + 0) * PP + p], a0);
        a1 = fmaf(decb[d + 1], Wq[(d + 1) * PP + p], a1);
        a2 = fmaf(decb[d + 2], Wq[(d + 2) * PP + p], a2);
        a3 = fmaf(decb[d + 3], Wq[(d + 3) * PP + p], a3);
    }
    const float acc = (a0 + a1) + (a2 + a3);

    __shared__ float s_red[256];
    s_red[tid] = acc;
    __syncthreads();
    if (tid < 64) {
        float r = s_red[tid] + s_red[tid + 64] + s_red[tid + 128] + s_red[tid + 192];
        q[b * PP + p] = r + bq[p];
    }
}

// ---------------------------------------------------------------------------
// K2: qk[b,e] = Wk[e,:] . q[b,:]
// grid = B*32 (16 e's per block), 256 thr = 16 groups of 16 lanes.
// ---------------------------------------------------------------------------
__global__ __launch_bounds__(256) void k_kfold(
    const float* __restrict__ Wk, const float* __restrict__ q,
    float* __restrict__ qk)
{
    const int b   = blockIdx.x >> 5;
    const int et  = blockIdx.x & 31;
    const int grp = threadIdx.x >> 4;
    const int l16 = threadIdx.x & 15;
    const int e   = et * 16 + grp;

    const float* wrow = Wk + e * PP;
    const float* qb   = q + b * PP;

    float s0 = 0.f, s1 = 0.f, s2 = 0.f, s3 = 0.f;
    #pragma unroll
    for (int k = 0; k < 4; ++k) {
        const float4 w  = *(const float4*)(wrow + l16 * 4 + k * 64);
        const float4 qv = *(const float4*)(qb   + l16 * 4 + k * 64);
        s0 = fmaf(w.x, qv.x, s0);
        s1 = fmaf(w.y, qv.y, s1);
        s2 = fmaf(w.z, qv.z, s2);
        s3 = fmaf(w.w, qv.w, s3);
    }
    float acc = (s0 + s1) + (s2 + s3);
    #pragma unroll
    for (int off = 1; off < 16; off <<= 1)
        acc += __shfl_xor(acc, off, 64);
    if (l16 == 0) qk[b * EH + e] = acc;
}

// ---------------------------------------------------------------------------
// K3: streaming pass over enc with online softmax.
// grid = B*NC = 512 blocks, 512 thr (8 waves), 32 rows/wave, depth-1 prefetch.
// Raw scores staged in LDS, one coalesced block store at the end.
// ---------------------------------------------------------------------------
__global__ __launch_bounds__(512) void attn_main(
    const float* __restrict__ enc,   // [B, T, EH]
    const float* __restrict__ qk,    // [B, EH]
    float* __restrict__ raw,         // [B, T]  (attn region of d_out)
    float* __restrict__ mc,          // [B, NC]
    float* __restrict__ lc,          // [B, NC]
    float* __restrict__ ctxc)        // [B, NC, EH]
{
    const int blk  = blockIdx.x;
    const int b    = blk >> 3;       // / NC
    const int c    = blk & (NC - 1);
    const int tid  = threadIdx.x;
    const int wave = tid >> 6;       // 0..7
    const int lane = tid & 63;
    const int e0   = lane * 4;

    const float* encb = enc + (size_t)b * TT * EH;

    const float4 qk0 = *(const float4*)(qk + b * EH + e0);
    const float4 qk1 = *(const float4*)(qk + b * EH + 256 + e0);

    float  m = -1e30f, l = 0.f;
    float4 ctx0 = {0.f, 0.f, 0.f, 0.f};
    float4 ctx1 = {0.f, 0.f, 0.f, 0.f};

    __shared__ float s_raw[TC];
    const int tbase = c * TC + wave;          // rows: tbase + WPB*it

    const vfloat4* row0 = (const vfloat4*)(encb + (size_t)tbase * EH);
    vfloat4 a0 = __builtin_nontemporal_load(row0 + lane);
    vfloat4 a1 = __builtin_nontemporal_load(row0 + 64 + lane);

    for (int it = 0; it < ROWS_PER_WAVE; ++it) {
        // prefetch next row (last iter: re-issue current row, L1-hot)
        const int itn = (it + 1 < ROWS_PER_WAVE) ? it + 1 : it;
        const vfloat4* nrow = (const vfloat4*)(encb + (size_t)(tbase + WPB * itn) * EH);
        vfloat4 n0 = __builtin_nontemporal_load(nrow + lane);
        vfloat4 n1 = __builtin_nontemporal_load(nrow + 64 + lane);

        float d = a0.x * qk0.x + a0.y * qk0.y + a0.z * qk0.z + a0.w * qk0.w
                + a1.x * qk1.x + a1.y * qk1.y + a1.z * qk1.z + a1.w * qk1.w;
        #pragma unroll
        for (int off = 32; off > 0; off >>= 1)
            d += __shfl_xor(d, off, 64);
        const float s = d;

        if (lane == 0) s_raw[wave + WPB * it] = s;

        const float mn    = fmaxf(m, s);
        const float scale = __expf(m - mn);
        const float p     = __expf(s - mn);
        l = l * scale + p;
        ctx0.x = ctx0.x * scale + p * a0.x;
        ctx0.y = ctx0.y * scale + p * a0.y;
        ctx0.z = ctx0.z * scale + p * a0.z;
        ctx0.w = ctx0.w * scale + p * a0.w;
        ctx1.x = ctx1.x * scale + p * a1.x;
        ctx1.y = ctx1.y * scale + p * a1.y;
        ctx1.z = ctx1.z * scale + p * a1.z;
        ctx1.w = ctx1.w * scale + p * a1.w;
        m = mn;

        a0 = n0; a1 = n1;
    }

    // merge the 8 waves of this block
    __shared__ float s_m[WPB], s_l[WPB];
    __shared__ float s_ctx[WPB][EH];
    *(float4*)&s_ctx[wave][e0]       = ctx0;
    *(float4*)&s_ctx[wave][256 + e0] = ctx1;
    if (lane == 0) { s_m[wave] = m; s_l[wave] = l; }
    __syncthreads();

    // coalesced raw-score store for this chunk (256 consecutive floats)
    if (tid < TC) raw[(size_t)b * TT + c * TC + tid] = s_raw[tid];

    float mb = s_m[0];
    #pragma unroll
    for (int i = 1; i < WPB; ++i) mb = fmaxf(mb, s_m[i]);
    float w[WPB];
    #pragma unroll
    for (int i = 0; i < WPB; ++i) w[i] = __expf(s_m[i] - mb);

    if (tid == 0) {
        float lsum = 0.f;
        #pragma unroll
        for (int i = 0; i < WPB; ++i) lsum = fmaf(s_l[i], w[i], lsum);
        mc[b * NC + c] = mb;
        lc[b * NC + c] = lsum;
    }
    // 512 threads, EH=512: one element each
    float accv = 0.f;
    #pragma unroll
    for (int i = 0; i < WPB; ++i) accv = fmaf(s_ctx[i][tid], w[i], accv);
    ctxc[((size_t)b * NC + c) * EH + tid] = accv;
}

// ---------------------------------------------------------------------------
// K4: per (b, p-quarter): merge chunk partials, context = sctx@Wv + bv,
// rewrite attn quarter. grid = B*4 = 256 blocks.
// ---------------------------------------------------------------------------
__global__ __launch_bounds__(256) void k_finish(
    const float* __restrict__ mc,    // [B, NC]
    const float* __restrict__ lc,    // [B, NC]
    const float* __restrict__ ctxc,  // [B, NC, EH]
    const float* __restrict__ Wv,    // [EH, PP]
    const float* __restrict__ bv,    // [PP]
    float* __restrict__ out_ctx,     // [B, PP]
    float* __restrict__ attn)        // [B, T] (holds raw on entry)
{
    const int b   = blockIdx.x >> 2;
    const int pq  = blockIdx.x & 3;
    const int tid = threadIdx.x;

    float m = -1e30f;
    #pragma unroll
    for (int i = 0; i < NC; ++i) m = fmaxf(m, mc[b * NC + i]);
    float l = 0.f;
    #pragma unroll
    for (int i = 0; i < NC; ++i) l += lc[b * NC + i] * __expf(mc[b * NC + i] - m);
    const float inv_l = 1.0f / l;

    __shared__ float s_w[NC];
    __shared__ float s_ctx[EH];
    if (tid < NC) s_w[tid] = __expf(mc[b * NC + tid] - m);
    __syncthreads();

    for (int e = tid; e < EH; e += 256) {
        float acc = 0.f;
        #pragma unroll
        for (int i = 0; i < NC; ++i)
            acc += ctxc[((size_t)b * NC + i) * EH + e] * s_w[i];
        s_ctx[e] = acc * inv_l;
    }
    __syncthreads();

    const int p  = pq * 64 + (tid & 63);
    const int dc = tid >> 6;
    float a0 = 0.f, a1 = 0.f, a2 = 0.f, a3 = 0.f;
    #pragma unroll 8
    for (int e = dc * 128; e < dc * 128 + 128; e += 4) {
        a0 = fmaf(s_ctx[e + 0], Wv[(e + 0) * PP + p], a0);
        a1 = fmaf(s_ctx[e + 1], Wv[(e + 1) * PP + p], a1);
        a2 = fmaf(s_ctx[e + 2], Wv[(e + 2) * PP + p], a2);
        a3 = fmaf(s_ctx[e + 3], Wv[(e + 3) * PP + p], a3);
    }
    const float acc = (a0 + a1) + (a2 + a3);

    __shared__ float s_red[256];
    s_red[tid] = acc;
    __syncthreads();
    if (tid < 64)
        out_ctx[b * PP + p] = s_red[tid] + s_red[tid + 64]
                            + s_red[tid + 128] + s_red[tid + 192] + bv[p];

    #pragma unroll
    for (int i = 0; i < TT / 4 / 256; ++i) {
        const int t = pq * (TT / 4) + i * 256 + tid;
        const float r = attn[(size_t)b * TT + t];
        attn[(size_t)b * TT + t] = __expf(r - m) * inv_l;
    }
}

// ---------------------------------------------------------------------------
extern "C" void kernel_launch(void* const* d_in, const int* in_sizes, int n_in,
                              void* d_out, int out_size, void* d_ws, size_t ws_size,
                              hipStream_t stream) {
    const float* dec = (const float*)d_in[0];
    const float* enc = (const float*)d_in[1];
    // d_in[2] = encoder_lens: unused by the reference computation
    const float* Wk  = (const float*)d_in[3];
    // d_in[4] = bk: drops out (softmax shift invariance)
    const float* Wv  = (const float*)d_in[5];
    const float* bv  = (const float*)d_in[6];
    const float* Wq  = (const float*)d_in[7];
    const float* bq  = (const float*)d_in[8];

    float* out_ctx = (float*)d_out;              // [B, PP]
    float* attn    = out_ctx + BB * PP;          // [B, T]

    float* q    = (float*)d_ws;                  // B*PP
    float* qk   = q + BB * PP;                   // B*EH
    float* mc   = qk + BB * EH;                  // B*NC
    float* lc   = mc + BB * NC;                  // B*NC
    float* ctxc = lc + BB * NC;                  // B*NC*EH

    k_qproj<<<BB * 4, 256, 0, stream>>>(dec, Wq, bq, q);
    k_kfold<<<BB * 32, 256, 0, stream>>>(Wk, q, qk);
    attn_main<<<BB * NC, 512, 0, stream>>>(enc, qk, attn, mc, lc, ctxc);
    k_finish<<<BB * 4, 256, 0, stream>>>(mc, lc, ctxc, Wv, bv, out_ctx, attn);
}